// Round 5
// baseline (644.014 us; speedup 1.0000x reference)
//
#include <hip/hip_runtime.h>
#include <hip/hip_fp16.h>

#define F_TOTAL 128
#define N_HEADS 8
#define HEAD_DIM 16
#define SCAN_ITEMS 1024   // items per block in the node-histogram scan

typedef float vf4 __attribute__((ext_vector_type(4)));
typedef int   vi4 __attribute__((ext_vector_type(4)));

// ---------------------------------------------------------------------------
// Kernel 1: per-head linear projections q,k,v = x_h @ W_h^T.
// q stays fp32; k,v stored INTERLEAVED fp16 half2 {k_f, v_f} per feature
// (512 B/node) so the hot kernel reads one dwordx4 per lane per pair.
// Pair histogram fused in (independent work, saves a dispatch).
// ---------------------------------------------------------------------------
__global__ __launch_bounds__(256) void proj_hist_kernel(
    const float* __restrict__ x,
    const float* __restrict__ wq,
    const float* __restrict__ wk,
    const float* __restrict__ wv,
    const int*   __restrict__ idx_i,
    float* __restrict__ q, __half2* __restrict__ kv,
    int*   __restrict__ hist,
    int n_nodes, int n_pairs)
{
    const int gid = blockIdx.x * 256 + threadIdx.x;
    const int stride = gridDim.x * 256;
    const int f = gid & (F_TOTAL - 1);

    float rq[16], rk[16], rv[16];
    const float4* wq4 = (const float4*)wq;
    const float4* wk4 = (const float4*)wk;
    const float4* wv4 = (const float4*)wv;
    #pragma unroll
    for (int d4 = 0; d4 < 4; ++d4) {
        float4 a = wq4[f * 4 + d4];
        rq[d4*4+0]=a.x; rq[d4*4+1]=a.y; rq[d4*4+2]=a.z; rq[d4*4+3]=a.w;
        float4 b = wk4[f * 4 + d4];
        rk[d4*4+0]=b.x; rk[d4*4+1]=b.y; rk[d4*4+2]=b.z; rk[d4*4+3]=b.w;
        float4 c = wv4[f * 4 + d4];
        rv[d4*4+0]=c.x; rv[d4*4+1]=c.y; rv[d4*4+2]=c.z; rv[d4*4+3]=c.w;
    }
    // lane holding x[n][h*16+d] within this thread's wave
    const int lanebase = (f & 112) & 63;

    const int total = n_nodes * F_TOTAL;
    for (int idx = gid; idx < total; idx += stride) {
        const float xval = __builtin_nontemporal_load(x + idx);  // read-once
        float aq = 0.f, ak = 0.f, av = 0.f;
        #pragma unroll
        for (int d = 0; d < 16; ++d) {
            const float xv = __shfl(xval, lanebase + d);
            aq += xv * rq[d];
            ak += xv * rk[d];
            av += xv * rv[d];
        }
        q[idx] = aq;
        kv[idx] = __floats2half2_rn(ak, av);   // {k, v} for feature f
    }

    // fused pair histogram (grid covers 786k threads > 640k pairs)
    for (int p = gid; p < n_pairs; p += stride)
        atomicAdd(&hist[idx_i[p]], 1);
}

// ---------------------------------------------------------------------------
// Counting sort of pairs by idx_i: hist -> scan (2 dispatches) -> scatter.
// ---------------------------------------------------------------------------
__global__ __launch_bounds__(256) void scan_reduce_kernel(
    const int* __restrict__ hist, int* __restrict__ blockSums, int n)
{
    __shared__ int ls[256];
    const int t = threadIdx.x;
    const int base = blockIdx.x * SCAN_ITEMS + t * 4;
    int s = 0;
    if (base + 3 < n) {
        int4 h = *(const int4*)(hist + base);
        s = h.x + h.y + h.z + h.w;
    } else {
        for (int kk = 0; kk < 4; ++kk)
            if (base + kk < n) s += hist[base + kk];
    }
    ls[t] = s;
    __syncthreads();
    for (int off = 128; off > 0; off >>= 1) {
        if (t < off) ls[t] += ls[t + off];
        __syncthreads();
    }
    if (t == 0) blockSums[blockIdx.x] = ls[0];
}

// Spine fused in: each block redundantly sums blockSums[0..bid) itself.
__global__ __launch_bounds__(256) void scan_apply_kernel(
    const int* __restrict__ hist, const int* __restrict__ blockSums,
    int* __restrict__ offsets, int n, int nblk)
{
    __shared__ int ls[256];
    const int t = threadIdx.x;
    const int bid = blockIdx.x;

    // base = sum of blockSums[0..bid)
    int s = 0;
    for (int b = t; b < bid; b += 256) s += blockSums[b];
    ls[t] = s;
    __syncthreads();
    for (int off = 128; off > 0; off >>= 1) {
        if (t < off) ls[t] += ls[t + off];
        __syncthreads();
    }
    const int base0 = ls[0];
    __syncthreads();   // ls reused below

    const int base = bid * SCAN_ITEMS + t * 4;
    int h0 = 0, h1 = 0, h2 = 0, h3 = 0;
    if (base + 3 < n) {
        int4 h = *(const int4*)(hist + base);
        h0 = h.x; h1 = h.y; h2 = h.z; h3 = h.w;
    } else {
        if (base + 0 < n) h0 = hist[base + 0];
        if (base + 1 < n) h1 = hist[base + 1];
        if (base + 2 < n) h2 = hist[base + 2];
        if (base + 3 < n) h3 = hist[base + 3];
    }
    const int tsum = h0 + h1 + h2 + h3;
    ls[t] = tsum;
    __syncthreads();
    for (int off = 1; off < 256; off <<= 1) {
        int add = (t >= off) ? ls[t - off] : 0;
        __syncthreads();
        ls[t] += add;
        __syncthreads();
    }
    int off = base0 + (ls[t] - tsum);   // exclusive base
    if (base + 0 < n) offsets[base + 0] = off; off += h0;
    if (base + 1 < n) offsets[base + 1] = off; off += h1;
    if (base + 2 < n) offsets[base + 2] = off; off += h2;
    if (base + 3 < n) offsets[base + 3] = off;
}

// ---------------------------------------------------------------------------
// Scatter: 16 lanes per pair (4 pairs/wave). Reads w_ij SEQUENTIALLY
// (perfectly coalesced 512 B/pair), converts to fp16, and writes it to the
// pair's sorted slot (256 B = 2 full lines by 16 lanes) — this moves the
// w traffic out of segment's random-read path into a streamed read +
// posted random write here. meta shrinks to int2 {j, phi_bits} (p no
// longer needed downstream). offsets[] is bumped directly; segment
// recovers start = offsets[i] - hist[i].
// ---------------------------------------------------------------------------
__global__ __launch_bounds__(256) void scatter_kernel(
    const int* __restrict__ idx_i, const int* __restrict__ idx_j,
    const float* __restrict__ phi,
    const float* __restrict__ w_ij,
    int* __restrict__ offsets,
    int2* __restrict__ meta,
    __half* __restrict__ w16s,
    int n_pairs)
{
    const int grp = (blockIdx.x * 256 + threadIdx.x) >> 4;   // pair index
    const int l16 = threadIdx.x & 15;
    const int lane = threadIdx.x & 63;
    if (grp >= n_pairs) return;

    int pos = 0;
    if (l16 == 0) pos = atomicAdd(&offsets[idx_i[grp]], 1);
    pos = __shfl(pos, lane & 48);        // broadcast from l16==0 of this group

    // lane l16 handles features l16*8 .. l16*8+7
    const vf4 wa = __builtin_nontemporal_load(
        (const vf4*)(w_ij + (size_t)grp * F_TOTAL) + l16 * 2);
    const vf4 wb = __builtin_nontemporal_load(
        (const vf4*)(w_ij + (size_t)grp * F_TOTAL) + l16 * 2 + 1);
    union { vi4 i; __half2 h[4]; } o;
    o.h[0] = __floats2half2_rn(wa.x, wa.y);
    o.h[1] = __floats2half2_rn(wa.z, wa.w);
    o.h[2] = __floats2half2_rn(wb.x, wb.y);
    o.h[3] = __floats2half2_rn(wb.z, wb.w);
    *((vi4*)w16s + (size_t)pos * 16 + l16) = o.i;   // chunk = 256 B = 16 vi4

    if (l16 == 0)
        meta[pos] = (int2){idx_j[grp], __float_as_int(phi[grp])};
}

// ---------------------------------------------------------------------------
// Kernel 3: segmented attention aggregation — one node per wave.
// Lanes 0-31 even pair slots, 32-63 odd slots of the same node; thread
// t=lane&31 owns features 4t..4t+3. Per pair per lane: one b64 fp16 w load
// (SEQUENTIAL: w16s is in sorted order, halves fuse to 512-B wave reads),
// one dwordx4 fp16 {k,v} gather (L3), one b64 meta broadcast. Head reduce
// = shfl_xor 1,2; final shfl_xor(.,32) merges halves. Depth-2 meta
// prefetch; meta has an 8-entry padded tail.
// ---------------------------------------------------------------------------
__global__ __launch_bounds__(256) void segment_kernel(
    const float* __restrict__ q,
    const __half2* __restrict__ kv,
    const __half* __restrict__ w16s,
    const int* __restrict__ hist,
    const int* __restrict__ offsets,
    const int2* __restrict__ meta,
    float* __restrict__ out,
    int n_nodes)
{
    const int node = blockIdx.x * 4 + (threadIdx.x >> 6);
    if (node >= n_nodes) return;
    const int lane = threadIdx.x & 63;
    const int half = lane >> 5;
    const int t    = lane & 31;

    const int cnt   = hist[node];
    const int start = offsets[node] - cnt;   // offsets were advanced by scatter
    const vf4 q4 = *((const vf4*)(q + (size_t)node * F_TOTAL) + t);

    vf4 acc = (vf4){0.f, 0.f, 0.f, 0.f};

    const int my0 = start + half;
    const int rem = (cnt > half) ? ((cnt - half + 1) >> 1) : 0;

    union HU { vi4 i; __half2 h[4]; };
    union WU { int2 i2; __half2 h[2]; };

    if (rem > 0) {
        int2 m0 = meta[my0];
        int2 m1 = meta[my0 + 2];          // padded tail: always safe
        int r = 0;
        for (; r + 2 <= rem; r += 2) {
            const int2 n0 = meta[my0 + 2 * (r + 2)];
            const int2 n1 = meta[my0 + 2 * (r + 3)];
            // my slots this iteration: A = my0+2r, B = my0+2r+2
            WU wA; wA.i2 = *(const int2*)(w16s + (size_t)(my0 + 2*r)     * F_TOTAL + t * 4);
            HU A;  A.i   = *((const vi4*)kv + (size_t)m0.x * 32 + t);
            WU wB; wB.i2 = *(const int2*)(w16s + (size_t)(my0 + 2*(r+1)) * F_TOTAL + t * 4);
            HU B;  B.i   = *((const vi4*)kv + (size_t)m1.x * 32 + t);

            const float2 wa0 = __half22float2(wA.h[0]);
            const float2 wa1 = __half22float2(wA.h[1]);
            const float2 wb0 = __half22float2(wB.h[0]);
            const float2 wb1 = __half22float2(wB.h[1]);
            const float2 a0 = __half22float2(A.h[0]);
            const float2 a1 = __half22float2(A.h[1]);
            const float2 a2 = __half22float2(A.h[2]);
            const float2 a3 = __half22float2(A.h[3]);
            const float2 b0 = __half22float2(B.h[0]);
            const float2 b1 = __half22float2(B.h[1]);
            const float2 b2 = __half22float2(B.h[2]);
            const float2 b3 = __half22float2(B.h[3]);

            float sA = q4.x*wa0.x*a0.x + q4.y*wa0.y*a1.x + q4.z*wa1.x*a2.x + q4.w*wa1.y*a3.x;
            float sB = q4.x*wb0.x*b0.x + q4.y*wb0.y*b1.x + q4.z*wb1.x*b2.x + q4.w*wb1.y*b3.x;
            sA += __shfl_xor(sA, 1); sA += __shfl_xor(sA, 2);   // 16-wide head sum
            sB += __shfl_xor(sB, 1); sB += __shfl_xor(sB, 2);
            const float alA = sA * 0.25f * __int_as_float(m0.y);
            const float alB = sB * 0.25f * __int_as_float(m1.y);
            acc.x += alA * a0.y; acc.y += alA * a1.y;
            acc.z += alA * a2.y; acc.w += alA * a3.y;
            acc.x += alB * b0.y; acc.y += alB * b1.y;
            acc.z += alB * b2.y; acc.w += alB * b3.y;
            m0 = n0; m1 = n1;
        }
        if (r < rem) {   // odd tail: one more pair from m0 (slot my0+2r)
            WU wA; wA.i2 = *(const int2*)(w16s + (size_t)(my0 + 2*r) * F_TOTAL + t * 4);
            HU A;  A.i   = *((const vi4*)kv + (size_t)m0.x * 32 + t);
            const float2 wa0 = __half22float2(wA.h[0]);
            const float2 wa1 = __half22float2(wA.h[1]);
            const float2 a0 = __half22float2(A.h[0]);
            const float2 a1 = __half22float2(A.h[1]);
            const float2 a2 = __half22float2(A.h[2]);
            const float2 a3 = __half22float2(A.h[3]);
            float sA = q4.x*wa0.x*a0.x + q4.y*wa0.y*a1.x + q4.z*wa1.x*a2.x + q4.w*wa1.y*a3.x;
            sA += __shfl_xor(sA, 1); sA += __shfl_xor(sA, 2);
            const float alA = sA * 0.25f * __int_as_float(m0.y);
            acc.x += alA * a0.y; acc.y += alA * a1.y;
            acc.z += alA * a2.y; acc.w += alA * a3.y;
        }
    }

    // merge the even-pair half with the odd-pair half
    acc.x += __shfl_xor(acc.x, 32);
    acc.y += __shfl_xor(acc.y, 32);
    acc.z += __shfl_xor(acc.z, 32);
    acc.w += __shfl_xor(acc.w, 32);
    if (half == 0)
        __builtin_nontemporal_store(acc, (vf4*)(out + (size_t)node * F_TOTAL) + t);
}

extern "C" void kernel_launch(void* const* d_in, const int* in_sizes, int n_in,
                              void* d_out, int out_size, void* d_ws, size_t ws_size,
                              hipStream_t stream)
{
    const float* x     = (const float*)d_in[0];
    const float* w_ij  = (const float*)d_in[1];
    const int*   idx_i = (const int*)d_in[2];
    const int*   idx_j = (const int*)d_in[3];
    const float* phi   = (const float*)d_in[4];
    const float* wq    = (const float*)d_in[5];
    const float* wk    = (const float*)d_in[6];
    const float* wv    = (const float*)d_in[7];

    const int n_nodes = in_sizes[0] / F_TOTAL;
    const int n_pairs = in_sizes[2];
    const size_t node_elems = (size_t)n_nodes * F_TOTAL;

    // workspace layout (16B-aligned segments first)
    float*   q         = (float*)d_ws;                        // node_elems f32
    __half2* kv        = (__half2*)(q + node_elems);          // node_elems half2
    __half*  w16s      = (__half*)(kv + node_elems);          // n_pairs*128 fp16 (+1 chunk pad)
    int2*    meta      = (int2*)(w16s + (size_t)(n_pairs + 1) * F_TOTAL); // n_pairs+8
    int*     hist      = (int*)(meta + n_pairs + 8);          // n_nodes
    int*     offsets   = hist + n_nodes;                      // n_nodes
    int*     blockSums = offsets + n_nodes;                   // <=128

    hipMemsetAsync(hist, 0, (size_t)n_nodes * sizeof(int), stream);

    proj_hist_kernel<<<3072, 256, 0, stream>>>(
        x, wq, wk, wv, idx_i, q, kv, hist, n_nodes, n_pairs);

    const int nblk = (n_nodes + SCAN_ITEMS - 1) / SCAN_ITEMS;   // 98 for 100k
    scan_reduce_kernel<<<nblk, 256, 0, stream>>>(hist, blockSums, n_nodes);
    scan_apply_kernel<<<nblk, 256, 0, stream>>>(hist, blockSums, offsets,
                                                n_nodes, nblk);

    const int scat_blocks = (n_pairs * 16 + 255) / 256;
    scatter_kernel<<<scat_blocks, 256, 0, stream>>>(
        idx_i, idx_j, phi, w_ij, offsets, meta, w16s, n_pairs);

    segment_kernel<<<(n_nodes + 3) / 4, 256, 0, stream>>>(
        q, kv, w16s, hist, offsets, meta, (float*)d_out, n_nodes);
}

// Round 6
// 585.838 us; speedup vs baseline: 1.0993x; 1.0993x over previous
//
#include <hip/hip_runtime.h>
#include <hip/hip_fp16.h>

#define F_TOTAL 128
#define N_HEADS 8
#define HEAD_DIM 16
#define SCAN_ITEMS 1024   // items per block in the node-histogram scan

typedef float vf4 __attribute__((ext_vector_type(4)));
typedef int   vi4 __attribute__((ext_vector_type(4)));

// ---------------------------------------------------------------------------
// Kernel 1: per-head linear projections q,k,v = x_h @ W_h^T.
// q stored fp16 (halves its round trip: -51 MB vs fp32); k,v stored
// INTERLEAVED fp16 half2 {k_f, v_f} per feature (512 B/node) so the hot
// kernel reads one dwordx4 per lane per pair. Measured: dur is linear in
// HBM bytes at ~6.3 GB/ms (R4/R5 A/B), so every byte shaved pays directly.
// Pair histogram fused in (independent work, saves a dispatch).
// ---------------------------------------------------------------------------
__global__ __launch_bounds__(256) void proj_hist_kernel(
    const float* __restrict__ x,
    const float* __restrict__ wq,
    const float* __restrict__ wk,
    const float* __restrict__ wv,
    const int*   __restrict__ idx_i,
    __half* __restrict__ q16, __half2* __restrict__ kv,
    int*   __restrict__ hist,
    int n_nodes, int n_pairs)
{
    const int gid = blockIdx.x * 256 + threadIdx.x;
    const int stride = gridDim.x * 256;
    const int f = gid & (F_TOTAL - 1);

    float rq[16], rk[16], rv[16];
    const float4* wq4 = (const float4*)wq;
    const float4* wk4 = (const float4*)wk;
    const float4* wv4 = (const float4*)wv;
    #pragma unroll
    for (int d4 = 0; d4 < 4; ++d4) {
        float4 a = wq4[f * 4 + d4];
        rq[d4*4+0]=a.x; rq[d4*4+1]=a.y; rq[d4*4+2]=a.z; rq[d4*4+3]=a.w;
        float4 b = wk4[f * 4 + d4];
        rk[d4*4+0]=b.x; rk[d4*4+1]=b.y; rk[d4*4+2]=b.z; rk[d4*4+3]=b.w;
        float4 c = wv4[f * 4 + d4];
        rv[d4*4+0]=c.x; rv[d4*4+1]=c.y; rv[d4*4+2]=c.z; rv[d4*4+3]=c.w;
    }
    // lane holding x[n][h*16+d] within this thread's wave
    const int lanebase = (f & 112) & 63;

    const int total = n_nodes * F_TOTAL;
    for (int idx = gid; idx < total; idx += stride) {
        const float xval = __builtin_nontemporal_load(x + idx);  // read-once
        float aq = 0.f, ak = 0.f, av = 0.f;
        #pragma unroll
        for (int d = 0; d < 16; ++d) {
            const float xv = __shfl(xval, lanebase + d);
            aq += xv * rq[d];
            ak += xv * rk[d];
            av += xv * rv[d];
        }
        q16[idx] = __float2half_rn(aq);
        kv[idx] = __floats2half2_rn(ak, av);   // {k, v} for feature f
    }

    // fused pair histogram (grid covers 786k threads > 640k pairs)
    for (int p = gid; p < n_pairs; p += stride)
        atomicAdd(&hist[idx_i[p]], 1);
}

// ---------------------------------------------------------------------------
// Counting sort of pairs by idx_i: hist -> scan (2 dispatches) -> scatter.
// Payload packed into one int4 {p, j, phi_bits, 0}.
// ---------------------------------------------------------------------------
__global__ __launch_bounds__(256) void scan_reduce_kernel(
    const int* __restrict__ hist, int* __restrict__ blockSums, int n)
{
    __shared__ int ls[256];
    const int t = threadIdx.x;
    const int base = blockIdx.x * SCAN_ITEMS + t * 4;
    int s = 0;
    if (base + 3 < n) {
        int4 h = *(const int4*)(hist + base);
        s = h.x + h.y + h.z + h.w;
    } else {
        for (int kk = 0; kk < 4; ++kk)
            if (base + kk < n) s += hist[base + kk];
    }
    ls[t] = s;
    __syncthreads();
    for (int off = 128; off > 0; off >>= 1) {
        if (t < off) ls[t] += ls[t + off];
        __syncthreads();
    }
    if (t == 0) blockSums[blockIdx.x] = ls[0];
}

// Spine fused in: each block redundantly sums blockSums[0..bid) itself.
__global__ __launch_bounds__(256) void scan_apply_kernel(
    const int* __restrict__ hist, const int* __restrict__ blockSums,
    int* __restrict__ offsets, int n, int nblk)
{
    __shared__ int ls[256];
    const int t = threadIdx.x;
    const int bid = blockIdx.x;

    // base = sum of blockSums[0..bid)
    int s = 0;
    for (int b = t; b < bid; b += 256) s += blockSums[b];
    ls[t] = s;
    __syncthreads();
    for (int off = 128; off > 0; off >>= 1) {
        if (t < off) ls[t] += ls[t + off];
        __syncthreads();
    }
    const int base0 = ls[0];
    __syncthreads();   // ls reused below

    const int base = bid * SCAN_ITEMS + t * 4;
    int h0 = 0, h1 = 0, h2 = 0, h3 = 0;
    if (base + 3 < n) {
        int4 h = *(const int4*)(hist + base);
        h0 = h.x; h1 = h.y; h2 = h.z; h3 = h.w;
    } else {
        if (base + 0 < n) h0 = hist[base + 0];
        if (base + 1 < n) h1 = hist[base + 1];
        if (base + 2 < n) h2 = hist[base + 2];
        if (base + 3 < n) h3 = hist[base + 3];
    }
    const int tsum = h0 + h1 + h2 + h3;
    ls[t] = tsum;
    __syncthreads();
    for (int off = 1; off < 256; off <<= 1) {
        int add = (t >= off) ? ls[t - off] : 0;
        __syncthreads();
        ls[t] += add;
        __syncthreads();
    }
    int off = base0 + (ls[t] - tsum);   // exclusive base
    if (base + 0 < n) offsets[base + 0] = off; off += h0;
    if (base + 1 < n) offsets[base + 1] = off; off += h1;
    if (base + 2 < n) offsets[base + 2] = off; off += h2;
    if (base + 3 < n) offsets[base + 3] = off;
}

// scatter bumps offsets[] directly (no cursor array): afterwards
// offsets[i] == start_i + cnt_i, and the hot kernel recovers
// start_i = offsets[i] - hist[i].
__global__ __launch_bounds__(256) void scatter_kernel(
    const int* __restrict__ idx_i, const int* __restrict__ idx_j,
    const float* __restrict__ phi,
    int* __restrict__ offsets,
    vi4* __restrict__ meta,
    int n_pairs)
{
    const int p = blockIdx.x * 256 + threadIdx.x;
    if (p < n_pairs) {
        const int i = idx_i[p];
        const int pos = atomicAdd(&offsets[i], 1);
        meta[pos] = (vi4){p, idx_j[p], __float_as_int(phi[p]), 0};
    }
}

// ---------------------------------------------------------------------------
// Kernel 3: segmented attention aggregation — one node per wave (R4
// structure, proven best). Lanes 0-31 even pair slots, 32-63 odd slots of
// the same node; thread t=lane&31 owns features 4t..4t+3. Per pair per
// lane: one dwordx4 w load (nontemporal stream-once), ONE dwordx4 fp16
// {k,v} gather (L3-resident 51 MB set), head reduce = shfl_xor 1,2; final
// shfl_xor(.,32) merges halves. Depth-2 meta prefetch; meta has an
// 8-entry padded tail. q read as fp16 (8 B/lane).
// ---------------------------------------------------------------------------
__global__ __launch_bounds__(256) void segment_kernel(
    const __half* __restrict__ q16,
    const __half2* __restrict__ kv,
    const float* __restrict__ w_ij,
    const int* __restrict__ hist,
    const int* __restrict__ offsets,
    const vi4* __restrict__ meta,
    float* __restrict__ out,
    int n_nodes)
{
    const int node = blockIdx.x * 4 + (threadIdx.x >> 6);
    if (node >= n_nodes) return;
    const int lane = threadIdx.x & 63;
    const int half = lane >> 5;
    const int t    = lane & 31;

    const int cnt   = hist[node];
    const int start = offsets[node] - cnt;   // offsets were advanced by scatter

    union QU { int2 i2; __half2 h[2]; };
    QU qu; qu.i2 = *(const int2*)(q16 + (size_t)node * F_TOTAL + t * 4);
    const float2 ql = __half22float2(qu.h[0]);
    const float2 qh = __half22float2(qu.h[1]);
    const vf4 q4 = (vf4){ql.x, ql.y, qh.x, qh.y};

    vf4 acc = (vf4){0.f, 0.f, 0.f, 0.f};

    const int my0 = start + half;
    const int rem = (cnt > half) ? ((cnt - half + 1) >> 1) : 0;

    union HU { vi4 i; __half2 h[4]; };

    if (rem > 0) {
        vi4 m0 = meta[my0];
        vi4 m1 = meta[my0 + 2];          // padded tail: always safe
        int r = 0;
        for (; r + 2 <= rem; r += 2) {
            const vi4 n0 = meta[my0 + 2 * (r + 2)];
            const vi4 n1 = meta[my0 + 2 * (r + 3)];
            const vf4 wA = __builtin_nontemporal_load(
                (const vf4*)(w_ij + (size_t)m0.x * F_TOTAL) + t);
            HU A; A.i = *((const vi4*)kv + (size_t)m0.y * 32 + t);
            const vf4 wB = __builtin_nontemporal_load(
                (const vf4*)(w_ij + (size_t)m1.x * F_TOTAL) + t);
            HU B; B.i = *((const vi4*)kv + (size_t)m1.y * 32 + t);

            const float2 a0 = __half22float2(A.h[0]);
            const float2 a1 = __half22float2(A.h[1]);
            const float2 a2 = __half22float2(A.h[2]);
            const float2 a3 = __half22float2(A.h[3]);
            const float2 b0 = __half22float2(B.h[0]);
            const float2 b1 = __half22float2(B.h[1]);
            const float2 b2 = __half22float2(B.h[2]);
            const float2 b3 = __half22float2(B.h[3]);

            float sA = q4.x*wA.x*a0.x + q4.y*wA.y*a1.x + q4.z*wA.z*a2.x + q4.w*wA.w*a3.x;
            float sB = q4.x*wB.x*b0.x + q4.y*wB.y*b1.x + q4.z*wB.z*b2.x + q4.w*wB.w*b3.x;
            sA += __shfl_xor(sA, 1); sA += __shfl_xor(sA, 2);   // 16-wide head sum
            sB += __shfl_xor(sB, 1); sB += __shfl_xor(sB, 2);
            const float alA = sA * 0.25f * __int_as_float(m0.z);
            const float alB = sB * 0.25f * __int_as_float(m1.z);
            acc.x += alA * a0.y; acc.y += alA * a1.y;
            acc.z += alA * a2.y; acc.w += alA * a3.y;
            acc.x += alB * b0.y; acc.y += alB * b1.y;
            acc.z += alB * b2.y; acc.w += alB * b3.y;
            m0 = n0; m1 = n1;
        }
        if (r < rem) {   // odd tail: one more pair from m0
            const vf4 wA = __builtin_nontemporal_load(
                (const vf4*)(w_ij + (size_t)m0.x * F_TOTAL) + t);
            HU A; A.i = *((const vi4*)kv + (size_t)m0.y * 32 + t);
            const float2 a0 = __half22float2(A.h[0]);
            const float2 a1 = __half22float2(A.h[1]);
            const float2 a2 = __half22float2(A.h[2]);
            const float2 a3 = __half22float2(A.h[3]);
            float sA = q4.x*wA.x*a0.x + q4.y*wA.y*a1.x + q4.z*wA.z*a2.x + q4.w*wA.w*a3.x;
            sA += __shfl_xor(sA, 1); sA += __shfl_xor(sA, 2);
            const float alA = sA * 0.25f * __int_as_float(m0.z);
            acc.x += alA * a0.y; acc.y += alA * a1.y;
            acc.z += alA * a2.y; acc.w += alA * a3.y;
        }
    }

    // merge the even-pair half with the odd-pair half
    acc.x += __shfl_xor(acc.x, 32);
    acc.y += __shfl_xor(acc.y, 32);
    acc.z += __shfl_xor(acc.z, 32);
    acc.w += __shfl_xor(acc.w, 32);
    if (half == 0)
        __builtin_nontemporal_store(acc, (vf4*)(out + (size_t)node * F_TOTAL) + t);
}

extern "C" void kernel_launch(void* const* d_in, const int* in_sizes, int n_in,
                              void* d_out, int out_size, void* d_ws, size_t ws_size,
                              hipStream_t stream)
{
    const float* x     = (const float*)d_in[0];
    const float* w_ij  = (const float*)d_in[1];
    const int*   idx_i = (const int*)d_in[2];
    const int*   idx_j = (const int*)d_in[3];
    const float* phi   = (const float*)d_in[4];
    const float* wq    = (const float*)d_in[5];
    const float* wk    = (const float*)d_in[6];
    const float* wv    = (const float*)d_in[7];

    const int n_nodes = in_sizes[0] / F_TOTAL;
    const int n_pairs = in_sizes[2];
    const size_t node_elems = (size_t)n_nodes * F_TOTAL;

    // workspace layout (16B-aligned segments first)
    __half*  q16       = (__half*)d_ws;                   // node_elems fp16 (25.6MB)
    __half2* kv        = (__half2*)(q16 + node_elems);    // node_elems half2 (51.2MB)
    vi4*     meta      = (vi4*)(kv + node_elems);         // n_pairs + 8 (padded tail)
    int*     hist      = (int*)(meta + n_pairs + 8);      // n_nodes
    int*     offsets   = hist + n_nodes;                  // n_nodes
    int*     blockSums = offsets + n_nodes;               // <=128

    hipMemsetAsync(hist, 0, (size_t)n_nodes * sizeof(int), stream);

    proj_hist_kernel<<<3072, 256, 0, stream>>>(
        x, wq, wk, wv, idx_i, q16, kv, hist, n_nodes, n_pairs);

    const int nblk = (n_nodes + SCAN_ITEMS - 1) / SCAN_ITEMS;   // 98 for 100k
    scan_reduce_kernel<<<nblk, 256, 0, stream>>>(hist, blockSums, n_nodes);
    scan_apply_kernel<<<nblk, 256, 0, stream>>>(hist, blockSums, offsets,
                                                n_nodes, nblk);

    const int pair_blocks = (n_pairs + 255) / 256;
    scatter_kernel<<<pair_blocks, 256, 0, stream>>>(
        idx_i, idx_j, phi, offsets, meta, n_pairs);

    segment_kernel<<<(n_nodes + 3) / 4, 256, 0, stream>>>(
        q16, kv, w_ij, hist, offsets, meta, (float*)d_out, n_nodes);
}